// Round 2
// baseline (98.297 us; speedup 1.0000x reference)
//
#include <hip/hip_runtime.h>
#include <math.h>

#define N2C 32      // d_state/2, fast-path compile-time constant
#define BLK 128     // threads per h == l-stride of the recurrence

// ---------------------------------------------------------------------------
// Pre-kernel: per (h,n) derived params in double precision (cheap: 32K elems)
//   P[idx] = {dAr, dAi, Wr, Wi}   with W = exp(dA * BLK)
//   Q[idx] = {cr, ci, -, -}       with c' = 2*Cc*(exp(dA)-1)/A
// ---------------------------------------------------------------------------
__global__ __launch_bounds__(256) void s4d_pre(
    const float* __restrict__ log_dt,
    const float* __restrict__ A_imag,
    const float* __restrict__ log_A_real,
    const float* __restrict__ C,
    float4* __restrict__ P,
    float4* __restrict__ Q,
    int HN2, int N2)
{
    int idx = blockIdx.x * blockDim.x + threadIdx.x;
    if (idx >= HN2) return;
    int h = idx / N2;
    double dt  = exp((double)log_dt[h]);
    double Ar  = -exp((double)log_A_real[idx]);
    double Ai  = (double)A_imag[idx];
    double dAr = Ar * dt, dAi = Ai * dt;

    double eAr = exp(dAr) * cos(dAi);
    double eAi = exp(dAr) * sin(dAi);
    double tr = eAr - 1.0, ti = eAi;
    double Cr = (double)C[2 * idx], Ci = (double)C[2 * idx + 1];
    double nr = Cr * tr - Ci * ti;
    double ni = Cr * ti + Ci * tr;
    double inv = 1.0 / (Ar * Ar + Ai * Ai);
    double cr = 2.0 * (nr * Ar + ni * Ai) * inv;
    double ci = 2.0 * (ni * Ar - nr * Ai) * inv;

    double er = exp(dAr * (double)BLK);
    double ph = dAi * (double)BLK;
    double Wr = er * cos(ph), Wi = er * sin(ph);

    P[idx] = make_float4((float)dAr, (float)dAi, (float)Wr, (float)Wi);
    Q[idx] = make_float4((float)cr, (float)ci, 0.f, 0.f);
}

// ---------------------------------------------------------------------------
// Main kernel: block = one h, thread t owns l = t + BLK*j. Anchor via fast
// exp/sincos (amortized), then pure-FMA complex recurrence (no trans in loop).
// ---------------------------------------------------------------------------
template<bool PRE>
__global__ __launch_bounds__(BLK, 2) void s4d_main(
    const float4* __restrict__ P,
    const float4* __restrict__ Q,
    const float* __restrict__ log_dt,
    const float* __restrict__ A_imag,
    const float* __restrict__ log_A_real,
    const float* __restrict__ Cin,
    float* __restrict__ out,
    int L, int iters)
{
    int h = blockIdx.x;
    int t = threadIdx.x;
    int base = h * N2C;
    float tf = (float)t;

    float zr[N2C], zi[N2C], Wr[N2C], Wi[N2C];

#pragma unroll
    for (int n = 0; n < N2C; ++n) {
        float dAr, dAi, cr, ci;
        if constexpr (PRE) {
            float4 p = P[base + n];
            float4 q = Q[base + n];
            dAr = p.x; dAi = p.y; Wr[n] = p.z; Wi[n] = p.w;
            cr = q.x; ci = q.y;
        } else {
            float dt = __expf(log_dt[h]);
            float Ar = -__expf(log_A_real[base + n]);
            float Ai = A_imag[base + n];
            dAr = Ar * dt; dAi = Ai * dt;
            float er = __expf(dAr);
            float s, c; __sincosf(dAi, &s, &c);
            float trm = er * c - 1.0f, tim = er * s;
            float Cr = Cin[2 * (base + n)], Ci = Cin[2 * (base + n) + 1];
            float nr = Cr * trm - Ci * tim;
            float ni = Cr * tim + Ci * trm;
            float inv = 1.0f / (Ar * Ar + Ai * Ai);
            cr = 2.0f * (nr * Ar + ni * Ai) * inv;
            ci = 2.0f * (ni * Ar - nr * Ai) * inv;
            float er2 = __expf(dAr * (float)BLK);
            float s2, c2; __sincosf(dAi * (float)BLK, &s2, &c2);
            Wr[n] = er2 * c2; Wi[n] = er2 * s2;
        }
        // anchor z = c' * exp(dA * t)
        float e = __expf(dAr * tf);
        float s, c; __sincosf(dAi * tf, &s, &c);
        zr[n] = e * (cr * c - ci * s);
        zi[n] = e * (cr * s + ci * c);
    }

    float* o = out + (size_t)h * L + t;
    for (int j = 0; j < iters; ++j) {
        // tree-ish sum of real parts (4 parallel chains for ILP)
        float a0 = 0.f, a1 = 0.f, a2 = 0.f, a3 = 0.f;
#pragma unroll
        for (int n = 0; n < N2C; n += 4) {
            a0 += zr[n];
            a1 += zr[n + 1];
            a2 += zr[n + 2];
            a3 += zr[n + 3];
        }
        int l = j * BLK;
        if (l + t < L) o[l] = (a0 + a1) + (a2 + a3);

        if (j + 1 < iters) {
#pragma unroll
            for (int n = 0; n < N2C; ++n) {
                float nr = fmaf(-zi[n], Wi[n], zr[n] * Wr[n]);
                float ni = fmaf( zr[n], Wi[n], zi[n] * Wr[n]);
                zr[n] = nr; zi[n] = ni;
            }
        }
    }
}

// ---------------------------------------------------------------------------
// Generic fallback (shape-robust, direct eval) — only if N2 != 32
// ---------------------------------------------------------------------------
__global__ void s4d_generic(
    const float* __restrict__ log_dt,
    const float* __restrict__ A_imag,
    const float* __restrict__ log_A_real,
    const float* __restrict__ C,
    float* __restrict__ out,
    int H, int N2, int L)
{
    int idx = blockIdx.x * blockDim.x + threadIdx.x;
    if (idx >= H * L) return;
    int h = idx / L, l = idx - h * L;
    float dt = __expf(log_dt[h]);
    float lf = (float)l;
    float acc = 0.f;
    for (int n = 0; n < N2; ++n) {
        int k = h * N2 + n;
        float Ar = -__expf(log_A_real[k]);
        float Ai = A_imag[k];
        float dAr = Ar * dt, dAi = Ai * dt;
        float er = __expf(dAr);
        float s, c; __sincosf(dAi, &s, &c);
        float trm = er * c - 1.f, tim = er * s;
        float Cr = C[2 * k], Ci = C[2 * k + 1];
        float nr = Cr * trm - Ci * tim;
        float ni = Cr * tim + Ci * trm;
        float inv = 1.f / (Ar * Ar + Ai * Ai);
        float cr = 2.f * (nr * Ar + ni * Ai) * inv;
        float ci = 2.f * (ni * Ar - nr * Ai) * inv;
        float el = __expf(dAr * lf);
        float sl, cl; __sincosf(dAi * lf, &sl, &cl);
        acc += el * (cr * cl - ci * sl);
    }
    out[idx] = acc;
}

extern "C" void kernel_launch(void* const* d_in, const int* in_sizes, int n_in,
                              void* d_out, int out_size, void* d_ws, size_t ws_size,
                              hipStream_t stream)
{
    const float* log_dt     = (const float*)d_in[0];
    const float* A_imag     = (const float*)d_in[1];
    const float* log_A_real = (const float*)d_in[2];
    const float* C          = (const float*)d_in[3];
    float* out = (float*)d_out;

    int H   = in_sizes[0];
    int HN2 = in_sizes[1];
    int N2  = HN2 / H;
    int L   = out_size / H;
    int iters = (L + BLK - 1) / BLK;

    size_t need = (size_t)HN2 * 2 * sizeof(float4);

    if (N2 == N2C) {
        if (ws_size >= need) {
            float4* P = (float4*)d_ws;
            float4* Q = P + HN2;
            s4d_pre<<<(HN2 + 255) / 256, 256, 0, stream>>>(
                log_dt, A_imag, log_A_real, C, P, Q, HN2, N2);
            s4d_main<true><<<H, BLK, 0, stream>>>(
                P, Q, log_dt, A_imag, log_A_real, C, out, L, iters);
        } else {
            s4d_main<false><<<H, BLK, 0, stream>>>(
                nullptr, nullptr, log_dt, A_imag, log_A_real, C, out, L, iters);
        }
    } else {
        int total = H * L;
        s4d_generic<<<(total + 255) / 256, 256, 0, stream>>>(
            log_dt, A_imag, log_A_real, C, out, H, N2, L);
    }
}

// Round 3
// 90.326 us; speedup vs baseline: 1.0883x; 1.0883x over previous
//
#include <hip/hip_runtime.h>
#include <math.h>

#define N2C 32      // d_state/2, fast-path compile-time constant
#define NP  16      // N2C/2 packed pairs
#define BLK 128     // threads per h == l-stride of the recurrence

typedef float f32x2 __attribute__((ext_vector_type(2)));

// ---------------------------------------------------------------------------
// Pre-kernel: per (h,n) derived params in double precision (cheap: 32K elems)
//   P[idx] = {dAr, dAi, Wr, Wi}   with W = exp(dA * BLK)
//   Q[idx] = {cr, ci, -, -}       with c' = 2*Cc*(exp(dA)-1)/A
// ---------------------------------------------------------------------------
__global__ __launch_bounds__(256) void s4d_pre(
    const float* __restrict__ log_dt,
    const float* __restrict__ A_imag,
    const float* __restrict__ log_A_real,
    const float* __restrict__ C,
    float4* __restrict__ P,
    float4* __restrict__ Q,
    int HN2, int N2)
{
    int idx = blockIdx.x * blockDim.x + threadIdx.x;
    if (idx >= HN2) return;
    int h = idx / N2;
    double dt  = exp((double)log_dt[h]);
    double Ar  = -exp((double)log_A_real[idx]);
    double Ai  = (double)A_imag[idx];
    double dAr = Ar * dt, dAi = Ai * dt;

    double eAr = exp(dAr) * cos(dAi);
    double eAi = exp(dAr) * sin(dAi);
    double tr = eAr - 1.0, ti = eAi;
    double Cr = (double)C[2 * idx], Ci = (double)C[2 * idx + 1];
    double nr = Cr * tr - Ci * ti;
    double ni = Cr * ti + Ci * tr;
    double inv = 1.0 / (Ar * Ar + Ai * Ai);
    double cr = 2.0 * (nr * Ar + ni * Ai) * inv;
    double ci = 2.0 * (ni * Ar - nr * Ai) * inv;

    double er = exp(dAr * (double)BLK);
    double ph = dAi * (double)BLK;
    double Wr = er * cos(ph), Wi = er * sin(ph);

    P[idx] = make_float4((float)dAr, (float)dAi, (float)Wr, (float)Wi);
    Q[idx] = make_float4((float)cr, (float)ci, 0.f, 0.f);
}

// ---------------------------------------------------------------------------
// Main kernel: block = one h, thread t owns l = t + BLK*j. Anchor via fast
// exp/sincos (amortized over 32 outputs), then pure packed-FMA complex
// recurrence — SoA pairs (states 2n,2n+1 share one f32x2) so LLVM selects
// v_pk_fma_f32 / v_pk_mul_f32 / v_pk_add_f32 (~2x fewer issue slots).
// ---------------------------------------------------------------------------
template<bool PRE>
__global__ __launch_bounds__(BLK, 2) void s4d_main(
    const float4* __restrict__ P,
    const float4* __restrict__ Q,
    const float* __restrict__ log_dt,
    const float* __restrict__ A_imag,
    const float* __restrict__ log_A_real,
    const float* __restrict__ Cin,
    float* __restrict__ out,
    int L, int iters)
{
    int h = blockIdx.x;
    int t = threadIdx.x;
    int base = h * N2C;
    float tf = (float)t;

    f32x2 zR[NP], zI[NP], WR[NP], WI[NP];

#pragma unroll
    for (int n = 0; n < N2C; ++n) {
        float dAr, dAi, cr, ci, wr, wi;
        if constexpr (PRE) {
            float4 p = P[base + n];
            float4 q = Q[base + n];
            dAr = p.x; dAi = p.y; wr = p.z; wi = p.w;
            cr = q.x; ci = q.y;
        } else {
            float dt = __expf(log_dt[h]);
            float Ar = -__expf(log_A_real[base + n]);
            float Ai = A_imag[base + n];
            dAr = Ar * dt; dAi = Ai * dt;
            float er = __expf(dAr);
            float s0, c0; __sincosf(dAi, &s0, &c0);
            float trm = er * c0 - 1.0f, tim = er * s0;
            float Cr = Cin[2 * (base + n)], Ci = Cin[2 * (base + n) + 1];
            float nr = Cr * trm - Ci * tim;
            float ni = Cr * tim + Ci * trm;
            float inv = 1.0f / (Ar * Ar + Ai * Ai);
            cr = 2.0f * (nr * Ar + ni * Ai) * inv;
            ci = 2.0f * (ni * Ar - nr * Ai) * inv;
            float er2 = __expf(dAr * (float)BLK);
            float s2, c2; __sincosf(dAi * (float)BLK, &s2, &c2);
            wr = er2 * c2; wi = er2 * s2;
        }
        // anchor z = c' * exp(dA * t)
        float e = __expf(dAr * tf);
        float s, c; __sincosf(dAi * tf, &s, &c);
        float ar = e * (cr * c - ci * s);
        float ai = e * (cr * s + ci * c);
        int g = n >> 1, m = n & 1;
        zR[g][m] = ar;  zI[g][m] = ai;
        WR[g][m] = wr;  WI[g][m] = wi;
    }

    float* o = out + (size_t)h * L + t;
    for (int j = 0; j < iters; ++j) {
        // packed sum of real parts (4 parallel chains for ILP)
        f32x2 a0 = {0.f, 0.f}, a1 = a0, a2 = a0, a3 = a0;
#pragma unroll
        for (int g = 0; g < NP; g += 4) {
            a0 += zR[g];
            a1 += zR[g + 1];
            a2 += zR[g + 2];
            a3 += zR[g + 3];
        }
        f32x2 s01 = a0 + a1, s23 = a2 + a3;
        f32x2 s = s01 + s23;
        int l = j * BLK;
        if (l + t < L) o[l] = s[0] + s[1];

        if (j + 1 < iters) {
#pragma unroll
            for (int g = 0; g < NP; ++g) {
                // complex mul per lane pair: 2 pk_mul + 2 pk_fma
                f32x2 nR = __builtin_elementwise_fma(-zI[g], WI[g], zR[g] * WR[g]);
                f32x2 nI = __builtin_elementwise_fma( zR[g], WI[g], zI[g] * WR[g]);
                zR[g] = nR; zI[g] = nI;
            }
        }
    }
}

// ---------------------------------------------------------------------------
// Generic fallback (shape-robust, direct eval) — only if N2 != 32
// ---------------------------------------------------------------------------
__global__ void s4d_generic(
    const float* __restrict__ log_dt,
    const float* __restrict__ A_imag,
    const float* __restrict__ log_A_real,
    const float* __restrict__ C,
    float* __restrict__ out,
    int H, int N2, int L)
{
    int idx = blockIdx.x * blockDim.x + threadIdx.x;
    if (idx >= H * L) return;
    int h = idx / L, l = idx - h * L;
    float dt = __expf(log_dt[h]);
    float lf = (float)l;
    float acc = 0.f;
    for (int n = 0; n < N2; ++n) {
        int k = h * N2 + n;
        float Ar = -__expf(log_A_real[k]);
        float Ai = A_imag[k];
        float dAr = Ar * dt, dAi = Ai * dt;
        float er = __expf(dAr);
        float s, c; __sincosf(dAi, &s, &c);
        float trm = er * c - 1.f, tim = er * s;
        float Cr = C[2 * k], Ci = C[2 * k + 1];
        float nr = Cr * trm - Ci * tim;
        float ni = Cr * tim + Ci * trm;
        float inv = 1.f / (Ar * Ar + Ai * Ai);
        float cr = 2.f * (nr * Ar + ni * Ai) * inv;
        float ci = 2.f * (ni * Ar - nr * Ai) * inv;
        float el = __expf(dAr * lf);
        float sl, cl; __sincosf(dAi * lf, &sl, &cl);
        acc += el * (cr * cl - ci * sl);
    }
    out[idx] = acc;
}

extern "C" void kernel_launch(void* const* d_in, const int* in_sizes, int n_in,
                              void* d_out, int out_size, void* d_ws, size_t ws_size,
                              hipStream_t stream)
{
    const float* log_dt     = (const float*)d_in[0];
    const float* A_imag     = (const float*)d_in[1];
    const float* log_A_real = (const float*)d_in[2];
    const float* C          = (const float*)d_in[3];
    float* out = (float*)d_out;

    int H   = in_sizes[0];
    int HN2 = in_sizes[1];
    int N2  = HN2 / H;
    int L   = out_size / H;
    int iters = (L + BLK - 1) / BLK;

    size_t need = (size_t)HN2 * 2 * sizeof(float4);

    if (N2 == N2C) {
        if (ws_size >= need) {
            float4* P = (float4*)d_ws;
            float4* Q = P + HN2;
            s4d_pre<<<(HN2 + 255) / 256, 256, 0, stream>>>(
                log_dt, A_imag, log_A_real, C, P, Q, HN2, N2);
            s4d_main<true><<<H, BLK, 0, stream>>>(
                P, Q, log_dt, A_imag, log_A_real, C, out, L, iters);
        } else {
            s4d_main<false><<<H, BLK, 0, stream>>>(
                nullptr, nullptr, log_dt, A_imag, log_A_real, C, out, L, iters);
        }
    } else {
        int total = H * L;
        s4d_generic<<<(total + 255) / 256, 256, 0, stream>>>(
            log_dt, A_imag, log_A_real, C, out, H, N2, L);
    }
}